// Round 14
// baseline (573.417 us; speedup 1.0000x reference)
//
#include <hip/hip_runtime.h>
#include <stdint.h>

#define SEQL 2048
#define DM 1024
#define NH 16
#define DHD 64
#define NB 4
#define MT 8192  // NB*SEQL tokens

typedef __attribute__((ext_vector_type(8))) short bf16x8;
typedef __attribute__((ext_vector_type(4))) float f32x4;

__device__ __forceinline__ unsigned short f2bf(float f) {
  uint32_t u = __builtin_bit_cast(uint32_t, f);
  return (unsigned short)((u + 0x7FFFu + ((u >> 16) & 1u)) >> 16);
}
__device__ __forceinline__ float bf2f(unsigned short h) {
  return __builtin_bit_cast(float, (uint32_t)h << 16);
}
__device__ __forceinline__ float fexp2(float x) {
  float r;
  asm volatile("v_exp_f32 %0, %1" : "=v"(r) : "v"(x));
  return r;
}
__device__ __forceinline__ uint32_t cvtpk(float lo, float hi) {
  uint32_t r;
  asm volatile("v_cvt_pk_bf16_f32 %0, %1, %2" : "=v"(r) : "v"(lo), "v"(hi));
  return r;
}
__device__ __forceinline__ void glds16(const void* g, void* l) {
  __builtin_amdgcn_global_load_lds(
      (const __attribute__((address_space(1))) void*)g,
      (__attribute__((address_space(3))) void*)l, 16, 0, 0);
}
__device__ __forceinline__ void bar() {
  asm volatile("" ::: "memory");
  __builtin_amdgcn_s_barrier();
  asm volatile("" ::: "memory");
}
__device__ __forceinline__ void vm8() { asm volatile("s_waitcnt vmcnt(8)" ::: "memory"); }
__device__ __forceinline__ void vm4() { asm volatile("s_waitcnt vmcnt(4)" ::: "memory"); }
__device__ __forceinline__ void vm2() { asm volatile("s_waitcnt vmcnt(2)" ::: "memory"); }
__device__ __forceinline__ void vm0() { asm volatile("s_waitcnt vmcnt(0)" ::: "memory"); }

// ---------------- 8-elem fp32 -> bf16 cast helper ----------------
__device__ __forceinline__ void cast8(const float* __restrict__ in,
                                      unsigned short* __restrict__ out, int i) {
  const float4* p = (const float4*)(in + (size_t)i * 8);
  float4 a = p[0], b = p[1];
  uint32_t w0 = f2bf(a.x) | ((uint32_t)f2bf(a.y) << 16);
  uint32_t w1 = f2bf(a.z) | ((uint32_t)f2bf(a.w) << 16);
  uint32_t w2 = f2bf(b.x) | ((uint32_t)f2bf(b.y) << 16);
  uint32_t w3 = f2bf(b.z) | ((uint32_t)f2bf(b.w) << 16);
  int4 v = {(int)w0, (int)w1, (int)w2, (int)w3};
  *(int4*)(out + (size_t)i * 8) = v;
}

// ---------------- fused: x + Wq + Wk + Wv casts (one launch) ----------------
__global__ __launch_bounds__(256) void cast_qkvx(
    const float* __restrict__ x, unsigned short* __restrict__ xb,
    const float* __restrict__ Wq, const float* __restrict__ Wk,
    const float* __restrict__ Wv, unsigned short* __restrict__ wbuf) {
  int bid = blockIdx.x, tid = threadIdx.x;
  if (bid < 4096) {
    cast8(x, xb, bid * 256 + tid);
  } else {
    int b2 = bid - 4096;
    int w = b2 >> 9;  // 0..2
    int i = (b2 & 511) * 256 + tid;
    const float* src = w == 0 ? Wq : (w == 1 ? Wk : Wv);
    cast8(src, wbuf + (size_t)w * 1048576, i);
  }
}

// ---------------- V transpose body (pi-permuted) ----------------------------
__device__ __forceinline__ void vtrans_body(
    const unsigned short* __restrict__ V, unsigned short* __restrict__ Vt,
    int blk, unsigned short (*td)[72], int tid) {
  const int t64 = blk & 31;
  const int b = (blk >> 5) & 3;
  const int h = blk >> 7;
  const int r = tid >> 3, c8 = (tid & 7) * 8;
  const unsigned short* src = V + (size_t)(b * SEQL + t64 * 64) * DM + h * 64;
#pragma unroll
  for (int half = 0; half < 2; half++) {
    int4 v = *(const int4*)(src + (size_t)(r + half * 32) * DM + c8);
    *(int4*)&td[r + half * 32][c8] = v;
  }
  __syncthreads();
  unsigned short* dst = Vt + (size_t)((h * 4 + b) * 64) * SEQL + t64 * 64;
#pragma unroll
  for (int half = 0; half < 2; half++) {
    int tk = tid + half * 256;
    int d = tk >> 3, tc = (tk & 7) * 8;
    int gq = (tc >> 3) & 3;
    int b32 = tc & 32;
    unsigned short tmp[8];
#pragma unroll
    for (int j = 0; j < 8; j++)
      tmp[j] = td[b32 + gq * 4 + (j & 3) + 16 * (j >> 2)][d];
    *(int4*)(dst + (size_t)d * SEQL + tc) = *(int4*)tmp;
  }
}

// ---------------- attention pass 1 body: l = sum_t exp2(score) --------------
__device__ __forceinline__ void stats_body(
    const unsigned short* __restrict__ Q, const unsigned short* __restrict__ Kb,
    float* __restrict__ lst, int blk, unsigned short* sK, int tid) {
  const int sblk = blk & 15;
  const int bh = blk >> 4;
  const int b = bh >> 4, h = bh & 15;
  const int wid = tid >> 6, lane = tid & 63;
  const int g = lane >> 4, ln = lane & 15;
  const int s0 = sblk * 128 + wid * 32;

  bf16x8 q[2][2];
#pragma unroll
  for (int s = 0; s < 2; s++) {
    const unsigned short* qp =
        Q + (size_t)(b * SEQL + s0 + s * 16 + ln) * DM + h * DHD + g * 8;
    q[s][0] = *(const bf16x8*)qp;
    q[s][1] = *(const bf16x8*)(qp + 32);
  }

  const int srow = tid >> 3;
  const int sch = (tid & 7) ^ (srow & 7);
  const unsigned short* kg =
      Kb + (size_t)(b * SEQL + srow) * DM + h * DHD + sch * 8;

  auto stage = [&](int buf, int t0) {
    glds16(kg + (size_t)t0 * DM, (char*)sK + buf * 8192 + wid * 1024);
    glds16(kg + (size_t)(t0 + 32) * DM, (char*)sK + buf * 8192 + 4096 + wid * 1024);
  };

  float lsum[2] = {0.f, 0.f};
  const int NT = SEQL / 64;
  stage(0, 0);
  vm0();
  bar();
  int cur = 0;
  for (int i = 0; i < NT; i++) {
    if (i + 1 < NT) {
      stage(cur ^ 1, (i + 1) * 64);
      vm2();
    } else {
      vm0();
    }
    bar();
#pragma unroll
    for (int tt = 0; tt < 4; tt++) {
      int row = tt * 16 + ln;
      const char* base = (const char*)sK + cur * 8192 + row * 128;
      bf16x8 k0 = *(const bf16x8*)(base + ((g ^ (row & 7)) << 4));
      bf16x8 k1 = *(const bf16x8*)(base + (((4 + g) ^ (row & 7)) << 4));
      f32x4 sa = {0.f, 0.f, 0.f, 0.f}, sb = {0.f, 0.f, 0.f, 0.f};
      __builtin_amdgcn_s_setprio(1);
      sa = __builtin_amdgcn_mfma_f32_16x16x32_bf16(k0, q[0][0], sa, 0, 0, 0);
      sa = __builtin_amdgcn_mfma_f32_16x16x32_bf16(k1, q[0][1], sa, 0, 0, 0);
      sb = __builtin_amdgcn_mfma_f32_16x16x32_bf16(k0, q[1][0], sb, 0, 0, 0);
      sb = __builtin_amdgcn_mfma_f32_16x16x32_bf16(k1, q[1][1], sb, 0, 0, 0);
      __builtin_amdgcn_s_setprio(0);
      lsum[0] += fexp2(sa[0]) + fexp2(sa[1]) + fexp2(sa[2]) + fexp2(sa[3]);
      lsum[1] += fexp2(sb[0]) + fexp2(sb[1]) + fexp2(sb[2]) + fexp2(sb[3]);
    }
    bar();
    cur ^= 1;
  }
#pragma unroll
  for (int s = 0; s < 2; s++) {
    lsum[s] += __shfl_xor(lsum[s], 16);
    lsum[s] += __shfl_xor(lsum[s], 32);
    if (lane < 16) lst[(size_t)bh * SEQL + s0 + s * 16 + lane] = lsum[s];
  }
}

// ---------------- fused: vtrans + attn_stats (one launch) -------------------
__global__ __launch_bounds__(256, 4) void vtrans_stats(
    const unsigned short* __restrict__ V, unsigned short* __restrict__ Vt,
    const unsigned short* __restrict__ Q, const unsigned short* __restrict__ Kb,
    float* __restrict__ lst) {
  __shared__ __align__(16) unsigned short lbuf[2 * 64 * 64];  // 16 KB union
  int bid = blockIdx.x, tid = threadIdx.x;
  if (bid < 2048) {
    vtrans_body(V, Vt, bid, (unsigned short(*)[72])lbuf, tid);
  } else {
    int b2 = bid - 2048;
    stats_body(Q, Kb, lst, (b2 & 7) * 128 + (b2 >> 3), lbuf, tid);
  }
}

// ---------------- fused: addb (partial-O reduce) + Wo cast ------------------
__global__ __launch_bounds__(256) void addb_cast(
    const unsigned short* __restrict__ a, unsigned short* __restrict__ bio,
    const float* __restrict__ Wo, unsigned short* __restrict__ wbuf) {
  int bid = blockIdx.x, tid = threadIdx.x;
  if (bid < 4096) {
    int i = bid * 256 + tid;
    int4 va = *(const int4*)(a + (size_t)i * 8);
    int4 vb = *(const int4*)(bio + (size_t)i * 8);
    uint32_t* pa = (uint32_t*)&va;
    uint32_t* pb = (uint32_t*)&vb;
    int4 vo;
    uint32_t* po = (uint32_t*)&vo;
#pragma unroll
    for (int j = 0; j < 4; j++) {
      float lo = bf2f((unsigned short)pa[j]) + bf2f((unsigned short)pb[j]);
      float hi = bf2f((unsigned short)(pa[j] >> 16)) + bf2f((unsigned short)(pb[j] >> 16));
      po[j] = f2bf(lo) | ((uint32_t)f2bf(hi) << 16);
    }
    *(int4*)(bio + (size_t)i * 8) = vo;
  } else {
    cast8(Wo, wbuf, (bid - 4096) * 256 + tid);
  }
}

// ============ 8-phase 256-col GEMM (R8 ledger; kk-outer MFMA order) ========
// kk-outer raises same-acc dependency distance 1 -> MH*2 while keeping the
// per-accumulator summation order (kk=0 then kk=1) -> bit-identical results.
template <int MS, int NS, int MR, int MH>
__device__ __forceinline__ void mmaQ(f32x4 (&acc)[MR][4],
                                     const bf16x8 (&Ar)[MH][2],
                                     const bf16x8 (&Br)[2][2]) {
  __builtin_amdgcn_s_setprio(1);
#pragma unroll
  for (int kk = 0; kk < 2; kk++)
#pragma unroll
    for (int m = 0; m < MH; m++)
#pragma unroll
      for (int n = 0; n < 2; n++)
        acc[MS * MH + m][NS * 2 + n] = __builtin_amdgcn_mfma_f32_16x16x32_bf16(
            Ar[m][kk], Br[n][kk], acc[MS * MH + m][NS * 2 + n], 0, 0, 0);
  __builtin_amdgcn_s_setprio(0);
}

template <int MH>
__device__ __forceinline__ void loadF(bf16x8 (&Ar)[MH][2], const char* base,
                                      int row0, int g) {
#pragma unroll
  for (int m = 0; m < MH; m++) {
    int row = row0 + m * 16;
    int sw = (row & 7) << 4;
    Ar[m][0] = *(const bf16x8*)(base + row * 128 + ((g << 4) ^ sw));
    Ar[m][1] = *(const bf16x8*)(base + row * 128 + (((4 + g) << 4) ^ sw));
  }
}

template <int BM, bool RELU, int OMODE>  // OMODE 0:f32 1:bf16 2:QKV-split bf16
__global__ __launch_bounds__(512, 2) void gemm8(
    const unsigned short* __restrict__ Ag, const unsigned short* __restrict__ Bg,
    const float* __restrict__ bias0, const float* __restrict__ bias1,
    const float* __restrict__ bias2, void* C0, void* C1, void* C2, int N, int K,
    float sc0) {
  constexpr int MR = BM / 32;
  constexpr int MH = MR / 2;
  constexpr int AT = BM * 128;
  constexpr int BT = 256 * 128;
  __shared__ __align__(16) char lds[2 * AT + 2 * BT];
  char* Ab0 = lds;
  char* Ab1 = lds + AT;
  char* Bb0 = lds + 2 * AT;
  char* Bb1 = lds + 2 * AT + BT;

  const int tid = threadIdx.x;
  const int wid = tid >> 6, lane = tid & 63;
  const int wr = wid >> 2, wc = wid & 3;
  const int g = lane >> 4, ln = lane & 15;

  const int nbx = N >> 8;
  const int nwg = gridDim.x;
  const int cpx = nwg >> 3;
  const int wg = (blockIdx.x & 7) * cpx + (blockIdx.x >> 3);
  const int bm = wg / nbx, bn = wg % nbx;

  f32x4 acc[MR][4];
#pragma unroll
  for (int m = 0; m < MR; m++)
#pragma unroll
    for (int n = 0; n < 4; n++) acc[m][n] = (f32x4){0.f, 0.f, 0.f, 0.f};

  const int srow = wid * 8 + (lane >> 3);
  const int cs8 = ((lane & 7) ^ (lane >> 3)) * 8;
  const unsigned short* aBase = Ag + (size_t)(bm * BM + srow) * K + cs8;
  const unsigned short* bBase = Bg + (size_t)(bn * 256 + srow) * K + cs8;
  const int wofs = wid * 1024;

  auto stageA = [&](char* buf, int tt, int h) {
    const unsigned short* src = aBase + (size_t)(h * (BM / 2)) * K + tt * 64;
    char* dst = buf + h * (AT / 2) + wofs;
    glds16(src, dst);
    if constexpr (BM == 256) glds16(src + (size_t)64 * K, dst + 8192);
  };
  auto stageB = [&](char* buf, int tt, int h) {
    const unsigned short* src = bBase + (size_t)(h * 128) * K + tt * 64;
    char* dst = buf + h * (BT / 2) + wofs;
    glds16(src, dst);
    glds16(src + (size_t)64 * K, dst + 8192);
  };

  const int np = K >> 7;
  const int rowA0 = wr * (BM / 2) + ln;
  const int rowB0 = wc * 64 + ln;

  stageA(Ab0, 0, 0);
  stageA(Ab0, 0, 1);
  stageB(Bb0, 0, 0);
  stageB(Bb0, 0, 1);
  stageB(Bb1, 1, 0);
  stageB(Bb1, 1, 1);
  vm4();
  bar();

  bf16x8 Ar0[MH][2], Ar1[MH][2], Br0[2][2], Br1[2][2];
  for (int i = 0; i < np; i++) {
    const int t = 2 * i;
    const bool sg = (i + 1 < np);
    // ---- P1 (buf0): all B-frags + A first half
    loadF<MH>(Ar0, Ab0, rowA0, g);
    loadF<2>(Br0, Bb0, rowB0, g);
    loadF<2>(Br1, Bb0, rowB0 + 32, g);
    stageA(Ab1, t + 1, 0);
    bar();
    mmaQ<0, 0>(acc, Ar0, Br0);
    bar();
    // ---- P2
    if constexpr (BM == 128) loadF<MH>(Ar1, Ab0, rowA0 + MH * 16, g);
    stageA(Ab1, t + 1, 1);
    bar();
    mmaQ<0, 1>(acc, Ar0, Br1);
    bar();
    // ---- P3
    if constexpr (BM == 256) loadF<MH>(Ar1, Ab0, rowA0 + MH * 16, g);
    if (sg) stageB(Bb0, t + 2, 0);
    bar();
    mmaQ<1, 1>(acc, Ar1, Br1);
    bar();
    // ---- P4
    if (sg) stageB(Bb0, t + 2, 1);
    bar();
    mmaQ<1, 0>(acc, Ar1, Br0);
    if (sg) vm4(); else vm0();
    bar();
    // ---- P5 (buf1)
    loadF<MH>(Ar0, Ab1, rowA0, g);
    loadF<2>(Br0, Bb1, rowB0, g);
    loadF<2>(Br1, Bb1, rowB0 + 32, g);
    if (sg) stageA(Ab0, t + 2, 0);
    bar();
    mmaQ<0, 0>(acc, Ar0, Br0);
    bar();
    // ---- P6
    if constexpr (BM == 128) loadF<MH>(Ar1, Ab1, rowA0 + MH * 16, g);
    if (sg) stageA(Ab0, t + 2, 1);
    bar();
    mmaQ<0, 1>(acc, Ar0, Br1);
    bar();
    // ---- P7
    if constexpr (BM == 256) loadF<MH>(Ar1, Ab1, rowA0 + MH * 16, g);
    if (sg) stageB(Bb1, t + 3, 0);
    bar();
    mmaQ<1, 1>(acc, Ar1, Br1);
    bar();
    // ---- P8
    if (sg) stageB(Bb1, t + 3, 1);
    bar();
    mmaQ<1, 0>(acc, Ar1, Br0);
    if (sg) vm4();
    bar();
  }

  const int c0 = bn * 256 + wc * 64;
  const float* bias = bias0;
  float scl = sc0;
  unsigned short* outb = (unsigned short*)C0;
  float* outf = (float*)C0;
  int ldC = N;
  if constexpr (OMODE == 2) {
    int seg = bn >> 2;
    bias = seg == 0 ? bias0 : (seg == 1 ? bias1 : bias2);
    outb = (unsigned short*)(seg == 0 ? C0 : (seg == 1 ? C1 : C2));
    scl = seg == 0 ? sc0 : 1.0f;
    ldC = 1024;
  }
#pragma unroll
  for (int am = 0; am < MR; am++) {
#pragma unroll
    for (int n = 0; n < 4; n++) {
      int col = c0 + n * 16 + ln;
      int colL = (OMODE == 2) ? (col & 1023) : col;
      float bv = bias[colL];
#pragma unroll
      for (int r = 0; r < 4; r++) {
        int row = bm * BM + wr * (BM / 2) + am * 16 + g * 4 + r;
        float v = (acc[am][n][r] + bv) * scl;
        if constexpr (RELU) v = fmaxf(v, 0.f);
        if constexpr (OMODE == 0)
          outf[(size_t)row * ldC + colL] = v;
        else
          outb[(size_t)row * ldC + colL] = f2bf(v);
      }
    }
  }
}

// ---------------- attention pass 2: A = sum_b softmax, O = A @ V -----------
__global__ __launch_bounds__(256, 2) void attn_apply(
    const unsigned short* __restrict__ Q, const unsigned short* __restrict__ Kb,
    const unsigned short* __restrict__ Vtp, const float* __restrict__ lst,
    unsigned short* __restrict__ op0, unsigned short* __restrict__ op1) {
  __shared__ unsigned short sK[2][4][32 * 64];
  __shared__ unsigned short sV[2][4][64 * 32];
  const int blk = (blockIdx.x & 7) * 64 + (blockIdx.x >> 3);
  const int tpart = blk & 1;
  const int sblk = (blk >> 1) & 15;
  const int h = blk >> 5;
  const int tid = threadIdx.x;
  const int wid = tid >> 6, lane = tid & 63;
  const int g = lane >> 4, ln = lane & 15;
  const int s0 = sblk * 128 + wid * 32;
  const int tbase = tpart * (SEQL / 2);

  bf16x8 q[2][4][2];
#pragma unroll
  for (int s = 0; s < 2; s++)
#pragma unroll
    for (int b = 0; b < 4; b++) {
      const unsigned short* qp =
          Q + (size_t)(b * SEQL + s0 + s * 16 + ln) * DM + h * DHD + g * 8;
      q[s][b][0] = *(const bf16x8*)qp;
      q[s][b][1] = *(const bf16x8*)(qp + 32);
    }
  float rl[2][4];
#pragma unroll
  for (int s = 0; s < 2; s++)
#pragma unroll
    for (int b = 0; b < 4; b++)
      rl[s][b] = 1.0f / lst[(size_t)(b * NH + h) * SEQL + s0 + s * 16 + ln];

  f32x4 o[2][4][4];
#pragma unroll
  for (int s = 0; s < 2; s++)
#pragma unroll
    for (int b = 0; b < 4; b++)
#pragma unroll
      for (int c = 0; c < 4; c++) o[s][b][c] = (f32x4){0.f, 0.f, 0.f, 0.f};

  const int krow = tid >> 3;
  const int kch = (tid & 7) ^ (krow & 7);
  const int vrow = wid * 16 + (lane >> 2);
  const int vch = (lane & 3) ^ ((vrow >> 1) & 3);
  const unsigned short* vbase = Vtp + (size_t)(h * 256 + vrow) * SEQL + vch * 8;
  const int vswz = (ln >> 1) & 3;

  auto stage = [&](int buf, int t0) {
#pragma unroll
    for (int b = 0; b < 4; b++)
      glds16(Kb + (size_t)(b * SEQL + t0 + krow) * DM + h * DHD + kch * 8,
             (char*)&sK[buf][b][0] + wid * 1024);
#pragma unroll
    for (int b = 0; b < 4; b++)
      glds16(vbase + (size_t)(b * 64) * SEQL + t0,
             (char*)&sV[buf][b][0] + wid * 1024);
  };

  const int NT = (SEQL / 2) / 32;
  stage(0, tbase);
  vm0();
  bar();
  int cur = 0;
  for (int i = 0; i < NT; i++) {
    if (i + 1 < NT) {
      stage(cur ^ 1, tbase + (i + 1) * 32);
      vm8();
    } else {
      vm0();
    }
    bar();

    float at0[2][4], at1[2][4];
#pragma unroll
    for (int tt = 0; tt < 2; tt++)
#pragma unroll
      for (int r = 0; r < 4; r++) { at0[tt][r] = 0.f; at1[tt][r] = 0.f; }
#pragma unroll
    for (int b = 0; b < 4; b++) {
#pragma unroll
      for (int tt = 0; tt < 2; tt++) {
        int row = tt * 16 + ln;
        const char* base = (const char*)&sK[cur][b][0] + row * 128;
        bf16x8 k0 = *(const bf16x8*)(base + ((g ^ (row & 7)) << 4));
        bf16x8 k1 = *(const bf16x8*)(base + (((4 + g) ^ (row & 7)) << 4));
        f32x4 sa = {0.f, 0.f, 0.f, 0.f}, sb = {0.f, 0.f, 0.f, 0.f};
        __builtin_amdgcn_s_setprio(1);
        sa = __builtin_amdgcn_mfma_f32_16x16x32_bf16(k0, q[0][b][0], sa, 0, 0, 0);
        sa = __builtin_amdgcn_mfma_f32_16x16x32_bf16(k1, q[0][b][1], sa, 0, 0, 0);
        sb = __builtin_amdgcn_mfma_f32_16x16x32_bf16(k0, q[1][b][0], sb, 0, 0, 0);
        sb = __builtin_amdgcn_mfma_f32_16x16x32_bf16(k1, q[1][b][1], sb, 0, 0, 0);
        __builtin_amdgcn_s_setprio(0);
#pragma unroll
        for (int r = 0; r < 4; r++) {
          at0[tt][r] = fmaf(fexp2(sa[r]), rl[0][b], at0[tt][r]);
          at1[tt][r] = fmaf(fexp2(sb[r]), rl[1][b], at1[tt][r]);
        }
      }
    }
    int4 aw0 = {(int)cvtpk(at0[0][0], at0[0][1]), (int)cvtpk(at0[0][2], at0[0][3]),
                (int)cvtpk(at0[1][0], at0[1][1]), (int)cvtpk(at0[1][2], at0[1][3])};
    int4 aw1 = {(int)cvtpk(at1[0][0], at1[0][1]), (int)cvtpk(at1[0][2], at1[0][3]),
                (int)cvtpk(at1[1][0], at1[1][1]), (int)cvtpk(at1[1][2], at1[1][3])};
    bf16x8 apk0 = __builtin_bit_cast(bf16x8, aw0);
    bf16x8 apk1 = __builtin_bit_cast(bf16x8, aw1);

    __builtin_amdgcn_s_setprio(1);
#pragma unroll
    for (int b = 0; b < 4; b++) {
#pragma unroll
      for (int c = 0; c < 4; c++) {
        int row = c * 16 + ln;
        const char* vb =
            (const char*)&sV[cur][b][0] + row * 64 + ((g ^ vswz) << 4);
        bf16x8 vf = *(const bf16x8*)vb;
        o[0][b][c] = __builtin_amdgcn_mfma_f32_16x16x32_bf16(apk0, vf, o[0][b][c], 0, 0, 0);
        o[1][b][c] = __builtin_amdgcn_mfma_f32_16x16x32_bf16(apk1, vf, o[1][b][c], 0, 0, 0);
      }
    }
    __builtin_amdgcn_s_setprio(0);
    bar();
    cur ^= 1;
  }

  unsigned short* op = tpart ? op1 : op0;
#pragma unroll
  for (int s = 0; s < 2; s++)
#pragma unroll
    for (int b = 0; b < 4; b++)
#pragma unroll
      for (int c = 0; c < 4; c++)
#pragma unroll
        for (int r = 0; r < 4; r++) {
          int srow = s0 + s * 16 + g * 4 + r;
          size_t off = (size_t)(b * SEQL + srow) * DM + h * DHD + c * 16 + ln;
          op[off] = f2bf(o[s][b][c][r]);
        }
}

// ---------------- layernorm body over D=1024; out bf16 ----------------------
template <bool ABF16, bool RESBF16>
__device__ __forceinline__ void ln_body(
    const void* __restrict__ a, const void* __restrict__ res,
    const float* __restrict__ gamma, const float* __restrict__ beta,
    unsigned short* __restrict__ obf, int row, int tid, float* red) {
  const size_t base = (size_t)row * DM + tid * 4;
  float a0, a1, a2, a3;
  if (ABF16) {
    ushort4 u = *(const ushort4*)((const unsigned short*)a + base);
    a0 = bf2f(u.x); a1 = bf2f(u.y); a2 = bf2f(u.z); a3 = bf2f(u.w);
  } else {
    float4 va = *(const float4*)((const float*)a + base);
    a0 = va.x; a1 = va.y; a2 = va.z; a3 = va.w;
  }
  float v0, v1, v2, v3;
  if (RESBF16) {
    ushort4 u = *(const ushort4*)((const unsigned short*)res + base);
    v0 = a0 + bf2f(u.x);
    v1 = a1 + bf2f(u.y);
    v2 = a2 + bf2f(u.z);
    v3 = a3 + bf2f(u.w);
  } else {
    float4 vr = *(const float4*)((const float*)res + base);
    v0 = a0 + vr.x;
    v1 = a1 + vr.y;
    v2 = a2 + vr.z;
    v3 = a3 + vr.w;
  }
  float sum = v0 + v1 + v2 + v3;
#pragma unroll
  for (int off = 1; off < 64; off <<= 1) sum += __shfl_xor(sum, off);
  const int wid = tid >> 6, lane = tid & 63;
  if (lane == 0) red[wid] = sum;
  __syncthreads();
  float mean = (red[0] + red[1] + red[2] + red[3]) * (1.0f / DM);
  float d0 = v0 - mean, d1 = v1 - mean, d2 = v2 - mean, d3 = v3 - mean;
  float sq = d0 * d0 + d1 * d1 + d2 * d2 + d3 * d3;
#pragma unroll
  for (int off = 1; off < 64; off <<= 1) sq += __shfl_xor(sq, off);
  if (lane == 0) red[4 + wid] = sq;
  __syncthreads();
  float var = (red[4] + red[5] + red[6] + red[7]) * (1.0f / DM);
  float rstd = rsqrtf(var + 1e-5f);
  float4 gm = *(const float4*)(gamma + tid * 4);
  float4 bb = *(const float4*)(beta + tid * 4);
  float o0 = gm.x * (d0 * rstd) + bb.x;
  float o1 = gm.y * (d1 * rstd) + bb.y;
  float o2 = gm.z * (d2 * rstd) + bb.z;
  float o3 = gm.w * (d3 * rstd) + bb.w;
  uint32_t w0 = f2bf(o0) | ((uint32_t)f2bf(o1) << 16);
  uint32_t w1 = f2bf(o2) | ((uint32_t)f2bf(o3) << 16);
  uint2 pk = {w0, w1};
  *(uint2*)(obf + base) = pk;
}

// LN2: a = ffo (bf16), res = ln1b (bf16)
__global__ __launch_bounds__(256) void ln_kernel2(
    const unsigned short* __restrict__ a, const unsigned short* __restrict__ res,
    const float* __restrict__ gamma, const float* __restrict__ beta,
    unsigned short* __restrict__ obf) {
  __shared__ float red[8];
  ln_body<true, true>(a, res, gamma, beta, obf, blockIdx.x, threadIdx.x, red);
}

// ---------------- fused: LN1 (a=bf16 aproj, res=f32 x) + weight casts -------
__global__ __launch_bounds__(256) void ln_cast5(
    const unsigned short* __restrict__ a, const float* __restrict__ res,
    const float* __restrict__ gamma, const float* __restrict__ beta,
    unsigned short* __restrict__ obf,
    const float* __restrict__ W1, const float* __restrict__ W2,
    const float* __restrict__ W3, const float* __restrict__ W4,
    const float* __restrict__ Wl,
    unsigned short* __restrict__ wbuf, unsigned short* __restrict__ w2p) {
  __shared__ float red[8];
  int bid = blockIdx.x, tid = threadIdx.x;
  if (bid < 8192) {
    ln_body<true, false>(a, res, gamma, beta, obf, bid, tid, red);
    return;
  }
  int b2 = bid - 8192;
  if (b2 < 2048) {
    cast8(W1, wbuf, b2 * 256 + tid);
  } else if (b2 < 6144) {
    cast8(W2, w2p, (b2 - 2048) * 256 + tid);
  } else if (b2 < 7168) {
    cast8(W3, wbuf + 4194304, (b2 - 6144) * 256 + tid);
  } else if (b2 < 7680) {
    cast8(W4, wbuf + 6291456, (b2 - 7168) * 256 + tid);
  } else {
    cast8(Wl, wbuf + 7340032, (b2 - 7680) * 256 + tid);
  }
}

// ---------------------------------------------------------------------------
extern "C" void kernel_launch(void* const* d_in, const int* in_sizes, int n_in,
                              void* d_out, int out_size, void* d_ws, size_t ws_size,
                              hipStream_t stream) {
  (void)in_sizes; (void)n_in; (void)out_size; (void)ws_size;
  const float* x  = (const float*)d_in[0];
  const float* Wq = (const float*)d_in[2];  const float* bq = (const float*)d_in[3];
  const float* Wk = (const float*)d_in[4];  const float* bk = (const float*)d_in[5];
  const float* Wv = (const float*)d_in[6];  const float* bv = (const float*)d_in[7];
  const float* Wo = (const float*)d_in[8];  const float* bo = (const float*)d_in[9];
  const float* gamma = (const float*)d_in[10]; const float* beta = (const float*)d_in[11];
  const float* W1 = (const float*)d_in[12]; const float* b1 = (const float*)d_in[13];
  const float* W2 = (const float*)d_in[14]; const float* b2 = (const float*)d_in[15];
  const float* W3 = (const float*)d_in[16]; const float* b3 = (const float*)d_in[17];
  const float* W4 = (const float*)d_in[18]; const float* b4 = (const float*)d_in[19];
  const float* Wl = (const float*)d_in[20]; const float* bl = (const float*)d_in[21];
  float* out = (float*)d_out;

  char* w = (char*)d_ws;
  const size_t MB = 1024 * 1024;
  unsigned short* xb   = (unsigned short*)(w);             // [0,16)
  unsigned short* Qb   = (unsigned short*)(w + 16 * MB);   // [16,32)
  unsigned short* Kbf  = (unsigned short*)(w + 32 * MB);   // [32,48)
  unsigned short* Vbf  = (unsigned short*)(w + 48 * MB);   // [48,64)
  float* lst = (float*)(w + 64 * MB);                      // 512KB
  unsigned short* ctx  = (unsigned short*)(w + 65 * MB);   // [65,81)
  unsigned short* wbuf = (unsigned short*)(w + 81 * MB);   // [81,97)
  unsigned short* ln1b = (unsigned short*)(w + 129 * MB);  // [129,145)
  // attention-phase aliases:
  unsigned short* Vt   = (unsigned short*)(w + 97 * MB);   // [97,129)
  unsigned short* op0  = (unsigned short*)(w);             // [0,16) (xb dead)
  // post-attention aliases:
  unsigned short* aprojb = (unsigned short*)(w + 97 * MB); // [97,113) bf16 (Vt dead)
  unsigned short* w2p  = ctx;                              // [65,81) (ctx dead post Wo-gemm)
  unsigned short* h1   = (unsigned short*)(w);             // [0,64)
  unsigned short* h2   = (unsigned short*)(w + 97 * MB);   // [97,129) (aprojb dead)
  unsigned short* h3   = (unsigned short*)(w + 65 * MB);   // [65,81) (w2p dead)
  unsigned short* ffob = (unsigned short*)(w);             // [0,16) bf16 (h1 dead)
  unsigned short* ln2b = (unsigned short*)(w + 32 * MB);   // [32,48)

  const float QSCALE = 0.125f * 1.44269504088896f;

  // 1. fused x + QKV-weight casts
  cast_qkvx<<<dim3(5632), dim3(256), 0, stream>>>(x, xb, Wq, Wk, Wv, wbuf);
  // 2. fused QKV GEMM (BM=256)
  gemm8<256, false, 2><<<dim3((MT / 256) * (3072 / 256)), dim3(512), 0, stream>>>(
      xb, wbuf, bq, bk, bv, Qb, Kbf, Vbf, 3072, 1024, QSCALE);
  // 3. fused V^T precompute + softmax denominators
  vtrans_stats<<<dim3(2048 + 1024), dim3(256), 0, stream>>>(Vbf, Vt, Qb, Kbf, lst);
  // 4. attention apply (A summed over batch)
  attn_apply<<<dim3(NH * 16 * 2), dim3(256), 0, stream>>>(Qb, Kbf, Vt, lst, op0, ctx);
  // 5. fused partial-O reduce + Wo cast
  addb_cast<<<dim3(4096 + 512), dim3(256), 0, stream>>>(op0, ctx, Wo, wbuf);
  // 6. output projection (bf16 out)
  gemm8<128, false, 1><<<dim3((MT / 128) * 4), dim3(512), 0, stream>>>(
      ctx, wbuf, bo, nullptr, nullptr, aprojb, nullptr, nullptr, 1024, 1024, 1.0f);
  // 7. fused LN1 (bf16 a + f32 res) + W1/W2/W3/W4/Wl casts
  ln_cast5<<<dim3(16384), dim3(256), 0, stream>>>(
      aprojb, x, gamma, beta, ln1b, W1, W2, W3, W4, Wl, wbuf, w2p);
  // 8-11. FFN chain
  gemm8<256, true, 1><<<dim3((MT / 256) * 16), dim3(512), 0, stream>>>(
      ln1b, wbuf, b1, nullptr, nullptr, h1, nullptr, nullptr, 4096, 1024, 1.0f);
  gemm8<256, true, 1><<<dim3((MT / 256) * 8), dim3(512), 0, stream>>>(
      h1, w2p, b2, nullptr, nullptr, h2, nullptr, nullptr, 2048, 4096, 1.0f);
  gemm8<128, true, 1><<<dim3((MT / 128) * 4), dim3(512), 0, stream>>>(
      h2, wbuf + 4194304, b3, nullptr, nullptr, h3, nullptr, nullptr, 1024, 2048, 1.0f);
  gemm8<128, false, 1><<<dim3((MT / 128) * 4), dim3(512), 0, stream>>>(
      h3, wbuf + 6291456, b4, nullptr, nullptr, ffob, nullptr, nullptr, 1024, 1024, 1.0f);
  // 12. LN2 (bf16 + bf16)
  ln_kernel2<<<dim3(MT), dim3(256), 0, stream>>>(ffob, ln1b, gamma, beta, ln2b);
  // 13. final projection -> d_out fp32
  gemm8<128, false, 0><<<dim3((MT / 128) * 4), dim3(512), 0, stream>>>(
      ln2b, wbuf + 7340032, bl, nullptr, nullptr, out, nullptr, nullptr, 1024, 1024, 1.0f);
}

// Round 15
// 560.912 us; speedup vs baseline: 1.0223x; 1.0223x over previous
//
#include <hip/hip_runtime.h>
#include <stdint.h>

#define SEQL 2048
#define DM 1024
#define NH 16
#define DHD 64
#define NB 4
#define MT 8192  // NB*SEQL tokens

typedef __attribute__((ext_vector_type(8))) short bf16x8;
typedef __attribute__((ext_vector_type(4))) float f32x4;

__device__ __forceinline__ unsigned short f2bf(float f) {
  uint32_t u = __builtin_bit_cast(uint32_t, f);
  return (unsigned short)((u + 0x7FFFu + ((u >> 16) & 1u)) >> 16);
}
__device__ __forceinline__ float bf2f(unsigned short h) {
  return __builtin_bit_cast(float, (uint32_t)h << 16);
}
__device__ __forceinline__ float fexp2(float x) {
  float r;
  asm volatile("v_exp_f32 %0, %1" : "=v"(r) : "v"(x));
  return r;
}
__device__ __forceinline__ uint32_t cvtpk(float lo, float hi) {
  uint32_t r;
  asm volatile("v_cvt_pk_bf16_f32 %0, %1, %2" : "=v"(r) : "v"(lo), "v"(hi));
  return r;
}
__device__ __forceinline__ void glds16(const void* g, void* l) {
  __builtin_amdgcn_global_load_lds(
      (const __attribute__((address_space(1))) void*)g,
      (__attribute__((address_space(3))) void*)l, 16, 0, 0);
}
__device__ __forceinline__ void bar() {
  asm volatile("" ::: "memory");
  __builtin_amdgcn_s_barrier();
  asm volatile("" ::: "memory");
}
__device__ __forceinline__ void vm8() { asm volatile("s_waitcnt vmcnt(8)" ::: "memory"); }
__device__ __forceinline__ void vm4() { asm volatile("s_waitcnt vmcnt(4)" ::: "memory"); }
__device__ __forceinline__ void vm2() { asm volatile("s_waitcnt vmcnt(2)" ::: "memory"); }
__device__ __forceinline__ void vm0() { asm volatile("s_waitcnt vmcnt(0)" ::: "memory"); }

// ---------------- 8-elem fp32 -> bf16 cast helper ----------------
__device__ __forceinline__ void cast8(const float* __restrict__ in,
                                      unsigned short* __restrict__ out, int i) {
  const float4* p = (const float4*)(in + (size_t)i * 8);
  float4 a = p[0], b = p[1];
  uint32_t w0 = f2bf(a.x) | ((uint32_t)f2bf(a.y) << 16);
  uint32_t w1 = f2bf(a.z) | ((uint32_t)f2bf(a.w) << 16);
  uint32_t w2 = f2bf(b.x) | ((uint32_t)f2bf(b.y) << 16);
  uint32_t w3 = f2bf(b.z) | ((uint32_t)f2bf(b.w) << 16);
  int4 v = {(int)w0, (int)w1, (int)w2, (int)w3};
  *(int4*)(out + (size_t)i * 8) = v;
}

// ---------------- fused: x + Wq + Wk + Wv casts (one launch) ----------------
__global__ __launch_bounds__(256) void cast_qkvx(
    const float* __restrict__ x, unsigned short* __restrict__ xb,
    const float* __restrict__ Wq, const float* __restrict__ Wk,
    const float* __restrict__ Wv, unsigned short* __restrict__ wbuf) {
  int bid = blockIdx.x, tid = threadIdx.x;
  if (bid < 4096) {
    cast8(x, xb, bid * 256 + tid);
  } else {
    int b2 = bid - 4096;
    int w = b2 >> 9;  // 0..2
    int i = (b2 & 511) * 256 + tid;
    const float* src = w == 0 ? Wq : (w == 1 ? Wk : Wv);
    cast8(src, wbuf + (size_t)w * 1048576, i);
  }
}

// ---------------- V transpose body (pi-permuted) ----------------------------
__device__ __forceinline__ void vtrans_body(
    const unsigned short* __restrict__ V, unsigned short* __restrict__ Vt,
    int blk, unsigned short (*td)[72], int tid) {
  const int t64 = blk & 31;
  const int b = (blk >> 5) & 3;
  const int h = blk >> 7;
  const int r = tid >> 3, c8 = (tid & 7) * 8;
  const unsigned short* src = V + (size_t)(b * SEQL + t64 * 64) * DM + h * 64;
#pragma unroll
  for (int half = 0; half < 2; half++) {
    int4 v = *(const int4*)(src + (size_t)(r + half * 32) * DM + c8);
    *(int4*)&td[r + half * 32][c8] = v;
  }
  __syncthreads();
  unsigned short* dst = Vt + (size_t)((h * 4 + b) * 64) * SEQL + t64 * 64;
#pragma unroll
  for (int half = 0; half < 2; half++) {
    int tk = tid + half * 256;
    int d = tk >> 3, tc = (tk & 7) * 8;
    int gq = (tc >> 3) & 3;
    int b32 = tc & 32;
    unsigned short tmp[8];
#pragma unroll
    for (int j = 0; j < 8; j++)
      tmp[j] = td[b32 + gq * 4 + (j & 3) + 16 * (j >> 2)][d];
    *(int4*)(dst + (size_t)d * SEQL + tc) = *(int4*)tmp;
  }
}

// ---------------- attention pass 1 body: l = sum_t exp2(score) --------------
__device__ __forceinline__ void stats_body(
    const unsigned short* __restrict__ Q, const unsigned short* __restrict__ Kb,
    float* __restrict__ lst, int blk, unsigned short* sK, int tid) {
  const int sblk = blk & 15;
  const int bh = blk >> 4;
  const int b = bh >> 4, h = bh & 15;
  const int wid = tid >> 6, lane = tid & 63;
  const int g = lane >> 4, ln = lane & 15;
  const int s0 = sblk * 128 + wid * 32;

  bf16x8 q[2][2];
#pragma unroll
  for (int s = 0; s < 2; s++) {
    const unsigned short* qp =
        Q + (size_t)(b * SEQL + s0 + s * 16 + ln) * DM + h * DHD + g * 8;
    q[s][0] = *(const bf16x8*)qp;
    q[s][1] = *(const bf16x8*)(qp + 32);
  }

  const int srow = tid >> 3;
  const int sch = (tid & 7) ^ (srow & 7);
  const unsigned short* kg =
      Kb + (size_t)(b * SEQL + srow) * DM + h * DHD + sch * 8;

  auto stage = [&](int buf, int t0) {
    glds16(kg + (size_t)t0 * DM, (char*)sK + buf * 8192 + wid * 1024);
    glds16(kg + (size_t)(t0 + 32) * DM, (char*)sK + buf * 8192 + 4096 + wid * 1024);
  };

  float lsum[2] = {0.f, 0.f};
  const int NT = SEQL / 64;
  stage(0, 0);
  vm0();
  bar();
  int cur = 0;
  for (int i = 0; i < NT; i++) {
    if (i + 1 < NT) {
      stage(cur ^ 1, (i + 1) * 64);
      vm2();
    } else {
      vm0();
    }
    bar();
#pragma unroll
    for (int tt = 0; tt < 4; tt++) {
      int row = tt * 16 + ln;
      const char* base = (const char*)sK + cur * 8192 + row * 128;
      bf16x8 k0 = *(const bf16x8*)(base + ((g ^ (row & 7)) << 4));
      bf16x8 k1 = *(const bf16x8*)(base + (((4 + g) ^ (row & 7)) << 4));
      f32x4 sa = {0.f, 0.f, 0.f, 0.f}, sb = {0.f, 0.f, 0.f, 0.f};
      __builtin_amdgcn_s_setprio(1);
      sa = __builtin_amdgcn_mfma_f32_16x16x32_bf16(k0, q[0][0], sa, 0, 0, 0);
      sa = __builtin_amdgcn_mfma_f32_16x16x32_bf16(k1, q[0][1], sa, 0, 0, 0);
      sb = __builtin_amdgcn_mfma_f32_16x16x32_bf16(k0, q[1][0], sb, 0, 0, 0);
      sb = __builtin_amdgcn_mfma_f32_16x16x32_bf16(k1, q[1][1], sb, 0, 0, 0);
      __builtin_amdgcn_s_setprio(0);
      lsum[0] += fexp2(sa[0]) + fexp2(sa[1]) + fexp2(sa[2]) + fexp2(sa[3]);
      lsum[1] += fexp2(sb[0]) + fexp2(sb[1]) + fexp2(sb[2]) + fexp2(sb[3]);
    }
    bar();
    cur ^= 1;
  }
#pragma unroll
  for (int s = 0; s < 2; s++) {
    lsum[s] += __shfl_xor(lsum[s], 16);
    lsum[s] += __shfl_xor(lsum[s], 32);
    if (lane < 16) lst[(size_t)bh * SEQL + s0 + s * 16 + lane] = lsum[s];
  }
}

// ---------------- fused: vtrans + attn_stats (one launch) -------------------
__global__ __launch_bounds__(256, 4) void vtrans_stats(
    const unsigned short* __restrict__ V, unsigned short* __restrict__ Vt,
    const unsigned short* __restrict__ Q, const unsigned short* __restrict__ Kb,
    float* __restrict__ lst) {
  __shared__ __align__(16) unsigned short lbuf[2 * 64 * 64];  // 16 KB union
  int bid = blockIdx.x, tid = threadIdx.x;
  if (bid < 2048) {
    vtrans_body(V, Vt, bid, (unsigned short(*)[72])lbuf, tid);
  } else {
    int b2 = bid - 2048;
    stats_body(Q, Kb, lst, (b2 & 7) * 128 + (b2 >> 3), lbuf, tid);
  }
}

// ---------------- fused: addb (partial-O reduce) + Wo cast ------------------
__global__ __launch_bounds__(256) void addb_cast(
    const unsigned short* __restrict__ a, unsigned short* __restrict__ bio,
    const float* __restrict__ Wo, unsigned short* __restrict__ wbuf) {
  int bid = blockIdx.x, tid = threadIdx.x;
  if (bid < 4096) {
    int i = bid * 256 + tid;
    int4 va = *(const int4*)(a + (size_t)i * 8);
    int4 vb = *(const int4*)(bio + (size_t)i * 8);
    uint32_t* pa = (uint32_t*)&va;
    uint32_t* pb = (uint32_t*)&vb;
    int4 vo;
    uint32_t* po = (uint32_t*)&vo;
#pragma unroll
    for (int j = 0; j < 4; j++) {
      float lo = bf2f((unsigned short)pa[j]) + bf2f((unsigned short)pb[j]);
      float hi = bf2f((unsigned short)(pa[j] >> 16)) + bf2f((unsigned short)(pb[j] >> 16));
      po[j] = f2bf(lo) | ((uint32_t)f2bf(hi) << 16);
    }
    *(int4*)(bio + (size_t)i * 8) = vo;
  } else {
    cast8(Wo, wbuf, (bid - 4096) * 256 + tid);
  }
}

// ============ 8-phase 256-col GEMM (R8/R13 configuration, known-good) ======
template <int MS, int NS, int MR, int MH>
__device__ __forceinline__ void mmaQ(f32x4 (&acc)[MR][4],
                                     const bf16x8 (&Ar)[MH][2],
                                     const bf16x8 (&Br)[2][2]) {
  __builtin_amdgcn_s_setprio(1);
#pragma unroll
  for (int m = 0; m < MH; m++)
#pragma unroll
    for (int n = 0; n < 2; n++)
#pragma unroll
      for (int kk = 0; kk < 2; kk++)
        acc[MS * MH + m][NS * 2 + n] = __builtin_amdgcn_mfma_f32_16x16x32_bf16(
            Ar[m][kk], Br[n][kk], acc[MS * MH + m][NS * 2 + n], 0, 0, 0);
  __builtin_amdgcn_s_setprio(0);
}

template <int MH>
__device__ __forceinline__ void loadF(bf16x8 (&Ar)[MH][2], const char* base,
                                      int row0, int g) {
#pragma unroll
  for (int m = 0; m < MH; m++) {
    int row = row0 + m * 16;
    int sw = (row & 7) << 4;
    Ar[m][0] = *(const bf16x8*)(base + row * 128 + ((g << 4) ^ sw));
    Ar[m][1] = *(const bf16x8*)(base + row * 128 + (((4 + g) << 4) ^ sw));
  }
}

template <int BM, bool RELU, int OMODE>  // OMODE 0:f32 1:bf16 2:QKV-split bf16
__global__ __launch_bounds__(512, 2) void gemm8(
    const unsigned short* __restrict__ Ag, const unsigned short* __restrict__ Bg,
    const float* __restrict__ bias0, const float* __restrict__ bias1,
    const float* __restrict__ bias2, void* C0, void* C1, void* C2, int N, int K,
    float sc0) {
  constexpr int MR = BM / 32;
  constexpr int MH = MR / 2;
  constexpr int AT = BM * 128;
  constexpr int BT = 256 * 128;
  __shared__ __align__(16) char lds[2 * AT + 2 * BT];
  char* Ab0 = lds;
  char* Ab1 = lds + AT;
  char* Bb0 = lds + 2 * AT;
  char* Bb1 = lds + 2 * AT + BT;

  const int tid = threadIdx.x;
  const int wid = tid >> 6, lane = tid & 63;
  const int wr = wid >> 2, wc = wid & 3;
  const int g = lane >> 4, ln = lane & 15;

  const int nbx = N >> 8;
  const int nwg = gridDim.x;
  const int cpx = nwg >> 3;
  const int wg = (blockIdx.x & 7) * cpx + (blockIdx.x >> 3);
  const int bm = wg / nbx, bn = wg % nbx;

  f32x4 acc[MR][4];
#pragma unroll
  for (int m = 0; m < MR; m++)
#pragma unroll
    for (int n = 0; n < 4; n++) acc[m][n] = (f32x4){0.f, 0.f, 0.f, 0.f};

  const int srow = wid * 8 + (lane >> 3);
  const int cs8 = ((lane & 7) ^ (lane >> 3)) * 8;
  const unsigned short* aBase = Ag + (size_t)(bm * BM + srow) * K + cs8;
  const unsigned short* bBase = Bg + (size_t)(bn * 256 + srow) * K + cs8;
  const int wofs = wid * 1024;

  auto stageA = [&](char* buf, int tt, int h) {
    const unsigned short* src = aBase + (size_t)(h * (BM / 2)) * K + tt * 64;
    char* dst = buf + h * (AT / 2) + wofs;
    glds16(src, dst);
    if constexpr (BM == 256) glds16(src + (size_t)64 * K, dst + 8192);
  };
  auto stageB = [&](char* buf, int tt, int h) {
    const unsigned short* src = bBase + (size_t)(h * 128) * K + tt * 64;
    char* dst = buf + h * (BT / 2) + wofs;
    glds16(src, dst);
    glds16(src + (size_t)64 * K, dst + 8192);
  };

  const int np = K >> 7;
  const int rowA0 = wr * (BM / 2) + ln;
  const int rowB0 = wc * 64 + ln;

  stageA(Ab0, 0, 0);
  stageA(Ab0, 0, 1);
  stageB(Bb0, 0, 0);
  stageB(Bb0, 0, 1);
  stageB(Bb1, 1, 0);
  stageB(Bb1, 1, 1);
  vm4();
  bar();

  bf16x8 Ar0[MH][2], Ar1[MH][2], Br0[2][2], Br1[2][2];
  for (int i = 0; i < np; i++) {
    const int t = 2 * i;
    const bool sg = (i + 1 < np);
    // ---- P1 (buf0): all B-frags + A first half
    loadF<MH>(Ar0, Ab0, rowA0, g);
    loadF<2>(Br0, Bb0, rowB0, g);
    loadF<2>(Br1, Bb0, rowB0 + 32, g);
    stageA(Ab1, t + 1, 0);
    bar();
    mmaQ<0, 0>(acc, Ar0, Br0);
    bar();
    // ---- P2
    if constexpr (BM == 128) loadF<MH>(Ar1, Ab0, rowA0 + MH * 16, g);
    stageA(Ab1, t + 1, 1);
    bar();
    mmaQ<0, 1>(acc, Ar0, Br1);
    bar();
    // ---- P3
    if constexpr (BM == 256) loadF<MH>(Ar1, Ab0, rowA0 + MH * 16, g);
    if (sg) stageB(Bb0, t + 2, 0);
    bar();
    mmaQ<1, 1>(acc, Ar1, Br1);
    bar();
    // ---- P4
    if (sg) stageB(Bb0, t + 2, 1);
    bar();
    mmaQ<1, 0>(acc, Ar1, Br0);
    if (sg) vm4(); else vm0();
    bar();
    // ---- P5 (buf1)
    loadF<MH>(Ar0, Ab1, rowA0, g);
    loadF<2>(Br0, Bb1, rowB0, g);
    loadF<2>(Br1, Bb1, rowB0 + 32, g);
    if (sg) stageA(Ab0, t + 2, 0);
    bar();
    mmaQ<0, 0>(acc, Ar0, Br0);
    bar();
    // ---- P6
    if constexpr (BM == 128) loadF<MH>(Ar1, Ab1, rowA0 + MH * 16, g);
    if (sg) stageA(Ab0, t + 2, 1);
    bar();
    mmaQ<0, 1>(acc, Ar0, Br1);
    bar();
    // ---- P7
    if constexpr (BM == 256) loadF<MH>(Ar1, Ab1, rowA0 + MH * 16, g);
    if (sg) stageB(Bb1, t + 3, 0);
    bar();
    mmaQ<1, 1>(acc, Ar1, Br1);
    bar();
    // ---- P8
    if (sg) stageB(Bb1, t + 3, 1);
    bar();
    mmaQ<1, 0>(acc, Ar1, Br0);
    if (sg) vm4();
    bar();
  }

  const int c0 = bn * 256 + wc * 64;
  const float* bias = bias0;
  float scl = sc0;
  unsigned short* outb = (unsigned short*)C0;
  float* outf = (float*)C0;
  int ldC = N;
  if constexpr (OMODE == 2) {
    int seg = bn >> 2;
    bias = seg == 0 ? bias0 : (seg == 1 ? bias1 : bias2);
    outb = (unsigned short*)(seg == 0 ? C0 : (seg == 1 ? C1 : C2));
    scl = seg == 0 ? sc0 : 1.0f;
    ldC = 1024;
  }
#pragma unroll
  for (int am = 0; am < MR; am++) {
#pragma unroll
    for (int n = 0; n < 4; n++) {
      int col = c0 + n * 16 + ln;
      int colL = (OMODE == 2) ? (col & 1023) : col;
      float bv = bias[colL];
#pragma unroll
      for (int r = 0; r < 4; r++) {
        int row = bm * BM + wr * (BM / 2) + am * 16 + g * 4 + r;
        float v = (acc[am][n][r] + bv) * scl;
        if constexpr (RELU) v = fmaxf(v, 0.f);
        if constexpr (OMODE == 0)
          outf[(size_t)row * ldC + colL] = v;
        else
          outb[(size_t)row * ldC + colL] = f2bf(v);
      }
    }
  }
}

// ---------------- attention pass 2: A = sum_b softmax, O = A @ V -----------
__global__ __launch_bounds__(256, 2) void attn_apply(
    const unsigned short* __restrict__ Q, const unsigned short* __restrict__ Kb,
    const unsigned short* __restrict__ Vtp, const float* __restrict__ lst,
    unsigned short* __restrict__ op0, unsigned short* __restrict__ op1) {
  __shared__ unsigned short sK[2][4][32 * 64];
  __shared__ unsigned short sV[2][4][64 * 32];
  const int blk = (blockIdx.x & 7) * 64 + (blockIdx.x >> 3);
  const int tpart = blk & 1;
  const int sblk = (blk >> 1) & 15;
  const int h = blk >> 5;
  const int tid = threadIdx.x;
  const int wid = tid >> 6, lane = tid & 63;
  const int g = lane >> 4, ln = lane & 15;
  const int s0 = sblk * 128 + wid * 32;
  const int tbase = tpart * (SEQL / 2);

  bf16x8 q[2][4][2];
#pragma unroll
  for (int s = 0; s < 2; s++)
#pragma unroll
    for (int b = 0; b < 4; b++) {
      const unsigned short* qp =
          Q + (size_t)(b * SEQL + s0 + s * 16 + ln) * DM + h * DHD + g * 8;
      q[s][b][0] = *(const bf16x8*)qp;
      q[s][b][1] = *(const bf16x8*)(qp + 32);
    }
  float rl[2][4];
#pragma unroll
  for (int s = 0; s < 2; s++)
#pragma unroll
    for (int b = 0; b < 4; b++)
      rl[s][b] = 1.0f / lst[(size_t)(b * NH + h) * SEQL + s0 + s * 16 + ln];

  f32x4 o[2][4][4];
#pragma unroll
  for (int s = 0; s < 2; s++)
#pragma unroll
    for (int b = 0; b < 4; b++)
#pragma unroll
      for (int c = 0; c < 4; c++) o[s][b][c] = (f32x4){0.f, 0.f, 0.f, 0.f};

  const int krow = tid >> 3;
  const int kch = (tid & 7) ^ (krow & 7);
  const int vrow = wid * 16 + (lane >> 2);
  const int vch = (lane & 3) ^ ((vrow >> 1) & 3);
  const unsigned short* vbase = Vtp + (size_t)(h * 256 + vrow) * SEQL + vch * 8;
  const int vswz = (ln >> 1) & 3;

  auto stage = [&](int buf, int t0) {
#pragma unroll
    for (int b = 0; b < 4; b++)
      glds16(Kb + (size_t)(b * SEQL + t0 + krow) * DM + h * DHD + kch * 8,
             (char*)&sK[buf][b][0] + wid * 1024);
#pragma unroll
    for (int b = 0; b < 4; b++)
      glds16(vbase + (size_t)(b * 64) * SEQL + t0,
             (char*)&sV[buf][b][0] + wid * 1024);
  };

  const int NT = (SEQL / 2) / 32;
  stage(0, tbase);
  vm0();
  bar();
  int cur = 0;
  for (int i = 0; i < NT; i++) {
    if (i + 1 < NT) {
      stage(cur ^ 1, tbase + (i + 1) * 32);
      vm8();
    } else {
      vm0();
    }
    bar();

    float at0[2][4], at1[2][4];
#pragma unroll
    for (int tt = 0; tt < 2; tt++)
#pragma unroll
      for (int r = 0; r < 4; r++) { at0[tt][r] = 0.f; at1[tt][r] = 0.f; }
#pragma unroll
    for (int b = 0; b < 4; b++) {
#pragma unroll
      for (int tt = 0; tt < 2; tt++) {
        int row = tt * 16 + ln;
        const char* base = (const char*)&sK[cur][b][0] + row * 128;
        bf16x8 k0 = *(const bf16x8*)(base + ((g ^ (row & 7)) << 4));
        bf16x8 k1 = *(const bf16x8*)(base + (((4 + g) ^ (row & 7)) << 4));
        f32x4 sa = {0.f, 0.f, 0.f, 0.f}, sb = {0.f, 0.f, 0.f, 0.f};
        __builtin_amdgcn_s_setprio(1);
        sa = __builtin_amdgcn_mfma_f32_16x16x32_bf16(k0, q[0][b][0], sa, 0, 0, 0);
        sa = __builtin_amdgcn_mfma_f32_16x16x32_bf16(k1, q[0][b][1], sa, 0, 0, 0);
        sb = __builtin_amdgcn_mfma_f32_16x16x32_bf16(k0, q[1][b][0], sb, 0, 0, 0);
        sb = __builtin_amdgcn_mfma_f32_16x16x32_bf16(k1, q[1][b][1], sb, 0, 0, 0);
        __builtin_amdgcn_s_setprio(0);
#pragma unroll
        for (int r = 0; r < 4; r++) {
          at0[tt][r] = fmaf(fexp2(sa[r]), rl[0][b], at0[tt][r]);
          at1[tt][r] = fmaf(fexp2(sb[r]), rl[1][b], at1[tt][r]);
        }
      }
    }
    int4 aw0 = {(int)cvtpk(at0[0][0], at0[0][1]), (int)cvtpk(at0[0][2], at0[0][3]),
                (int)cvtpk(at0[1][0], at0[1][1]), (int)cvtpk(at0[1][2], at0[1][3])};
    int4 aw1 = {(int)cvtpk(at1[0][0], at1[0][1]), (int)cvtpk(at1[0][2], at1[0][3]),
                (int)cvtpk(at1[1][0], at1[1][1]), (int)cvtpk(at1[1][2], at1[1][3])};
    bf16x8 apk0 = __builtin_bit_cast(bf16x8, aw0);
    bf16x8 apk1 = __builtin_bit_cast(bf16x8, aw1);

    __builtin_amdgcn_s_setprio(1);
#pragma unroll
    for (int b = 0; b < 4; b++) {
#pragma unroll
      for (int c = 0; c < 4; c++) {
        int row = c * 16 + ln;
        const char* vb =
            (const char*)&sV[cur][b][0] + row * 64 + ((g ^ vswz) << 4);
        bf16x8 vf = *(const bf16x8*)vb;
        o[0][b][c] = __builtin_amdgcn_mfma_f32_16x16x32_bf16(apk0, vf, o[0][b][c], 0, 0, 0);
        o[1][b][c] = __builtin_amdgcn_mfma_f32_16x16x32_bf16(apk1, vf, o[1][b][c], 0, 0, 0);
      }
    }
    __builtin_amdgcn_s_setprio(0);
    bar();
    cur ^= 1;
  }

  unsigned short* op = tpart ? op1 : op0;
#pragma unroll
  for (int s = 0; s < 2; s++)
#pragma unroll
    for (int b = 0; b < 4; b++)
#pragma unroll
      for (int c = 0; c < 4; c++)
#pragma unroll
        for (int r = 0; r < 4; r++) {
          int srow = s0 + s * 16 + g * 4 + r;
          size_t off = (size_t)(b * SEQL + srow) * DM + h * DHD + c * 16 + ln;
          op[off] = f2bf(o[s][b][c][r]);
        }
}

// ---------------- layernorm body over D=1024; out bf16 ----------------------
template <bool ABF16, bool RESBF16>
__device__ __forceinline__ void ln_body(
    const void* __restrict__ a, const void* __restrict__ res,
    const float* __restrict__ gamma, const float* __restrict__ beta,
    unsigned short* __restrict__ obf, int row, int tid, float* red) {
  const size_t base = (size_t)row * DM + tid * 4;
  float a0, a1, a2, a3;
  if (ABF16) {
    ushort4 u = *(const ushort4*)((const unsigned short*)a + base);
    a0 = bf2f(u.x); a1 = bf2f(u.y); a2 = bf2f(u.z); a3 = bf2f(u.w);
  } else {
    float4 va = *(const float4*)((const float*)a + base);
    a0 = va.x; a1 = va.y; a2 = va.z; a3 = va.w;
  }
  float v0, v1, v2, v3;
  if (RESBF16) {
    ushort4 u = *(const ushort4*)((const unsigned short*)res + base);
    v0 = a0 + bf2f(u.x);
    v1 = a1 + bf2f(u.y);
    v2 = a2 + bf2f(u.z);
    v3 = a3 + bf2f(u.w);
  } else {
    float4 vr = *(const float4*)((const float*)res + base);
    v0 = a0 + vr.x;
    v1 = a1 + vr.y;
    v2 = a2 + vr.z;
    v3 = a3 + vr.w;
  }
  float sum = v0 + v1 + v2 + v3;
#pragma unroll
  for (int off = 1; off < 64; off <<= 1) sum += __shfl_xor(sum, off);
  const int wid = tid >> 6, lane = tid & 63;
  if (lane == 0) red[wid] = sum;
  __syncthreads();
  float mean = (red[0] + red[1] + red[2] + red[3]) * (1.0f / DM);
  float d0 = v0 - mean, d1 = v1 - mean, d2 = v2 - mean, d3 = v3 - mean;
  float sq = d0 * d0 + d1 * d1 + d2 * d2 + d3 * d3;
#pragma unroll
  for (int off = 1; off < 64; off <<= 1) sq += __shfl_xor(sq, off);
  if (lane == 0) red[4 + wid] = sq;
  __syncthreads();
  float var = (red[4] + red[5] + red[6] + red[7]) * (1.0f / DM);
  float rstd = rsqrtf(var + 1e-5f);
  float4 gm = *(const float4*)(gamma + tid * 4);
  float4 bb = *(const float4*)(beta + tid * 4);
  float o0 = gm.x * (d0 * rstd) + bb.x;
  float o1 = gm.y * (d1 * rstd) + bb.y;
  float o2 = gm.z * (d2 * rstd) + bb.z;
  float o3 = gm.w * (d3 * rstd) + bb.w;
  uint32_t w0 = f2bf(o0) | ((uint32_t)f2bf(o1) << 16);
  uint32_t w1 = f2bf(o2) | ((uint32_t)f2bf(o3) << 16);
  uint2 pk = {w0, w1};
  *(uint2*)(obf + base) = pk;
}

// LN2: a = ffo (bf16), res = ln1b (bf16)
__global__ __launch_bounds__(256) void ln_kernel2(
    const unsigned short* __restrict__ a, const unsigned short* __restrict__ res,
    const float* __restrict__ gamma, const float* __restrict__ beta,
    unsigned short* __restrict__ obf) {
  __shared__ float red[8];
  ln_body<true, true>(a, res, gamma, beta, obf, blockIdx.x, threadIdx.x, red);
}

// ---------------- fused: LN1 (a=bf16 aproj, res=f32 x) + weight casts -------
__global__ __launch_bounds__(256) void ln_cast5(
    const unsigned short* __restrict__ a, const float* __restrict__ res,
    const float* __restrict__ gamma, const float* __restrict__ beta,
    unsigned short* __restrict__ obf,
    const float* __restrict__ W1, const float* __restrict__ W2,
    const float* __restrict__ W3, const float* __restrict__ W4,
    const float* __restrict__ Wl,
    unsigned short* __restrict__ wbuf, unsigned short* __restrict__ w2p) {
  __shared__ float red[8];
  int bid = blockIdx.x, tid = threadIdx.x;
  if (bid < 8192) {
    ln_body<true, false>(a, res, gamma, beta, obf, bid, tid, red);
    return;
  }
  int b2 = bid - 8192;
  if (b2 < 2048) {
    cast8(W1, wbuf, b2 * 256 + tid);
  } else if (b2 < 6144) {
    cast8(W2, w2p, (b2 - 2048) * 256 + tid);
  } else if (b2 < 7168) {
    cast8(W3, wbuf + 4194304, (b2 - 6144) * 256 + tid);
  } else if (b2 < 7680) {
    cast8(W4, wbuf + 6291456, (b2 - 7168) * 256 + tid);
  } else {
    cast8(Wl, wbuf + 7340032, (b2 - 7680) * 256 + tid);
  }
}

// ---------------------------------------------------------------------------
extern "C" void kernel_launch(void* const* d_in, const int* in_sizes, int n_in,
                              void* d_out, int out_size, void* d_ws, size_t ws_size,
                              hipStream_t stream) {
  (void)in_sizes; (void)n_in; (void)out_size; (void)ws_size;
  const float* x  = (const float*)d_in[0];
  const float* Wq = (const float*)d_in[2];  const float* bq = (const float*)d_in[3];
  const float* Wk = (const float*)d_in[4];  const float* bk = (const float*)d_in[5];
  const float* Wv = (const float*)d_in[6];  const float* bv = (const float*)d_in[7];
  const float* Wo = (const float*)d_in[8];  const float* bo = (const float*)d_in[9];
  const float* gamma = (const float*)d_in[10]; const float* beta = (const float*)d_in[11];
  const float* W1 = (const float*)d_in[12]; const float* b1 = (const float*)d_in[13];
  const float* W2 = (const float*)d_in[14]; const float* b2 = (const float*)d_in[15];
  const float* W3 = (const float*)d_in[16]; const float* b3 = (const float*)d_in[17];
  const float* W4 = (const float*)d_in[18]; const float* b4 = (const float*)d_in[19];
  const float* Wl = (const float*)d_in[20]; const float* bl = (const float*)d_in[21];
  float* out = (float*)d_out;

  char* w = (char*)d_ws;
  const size_t MB = 1024 * 1024;
  unsigned short* xb   = (unsigned short*)(w);             // [0,16)
  unsigned short* Qb   = (unsigned short*)(w + 16 * MB);   // [16,32)
  unsigned short* Kbf  = (unsigned short*)(w + 32 * MB);   // [32,48)
  unsigned short* Vbf  = (unsigned short*)(w + 48 * MB);   // [48,64)
  float* lst = (float*)(w + 64 * MB);                      // 512KB
  unsigned short* ctx  = (unsigned short*)(w + 65 * MB);   // [65,81)
  unsigned short* wbuf = (unsigned short*)(w + 81 * MB);   // [81,97)
  unsigned short* ln1b = (unsigned short*)(w + 129 * MB);  // [129,145)
  // attention-phase aliases:
  unsigned short* Vt   = (unsigned short*)(w + 97 * MB);   // [97,129)
  unsigned short* op0  = (unsigned short*)(w);             // [0,16) (xb dead)
  // post-attention aliases:
  unsigned short* aprojb = (unsigned short*)(w + 97 * MB); // [97,113) bf16 (Vt dead)
  unsigned short* w2p  = ctx;                              // [65,81) (ctx dead post Wo-gemm)
  unsigned short* h1   = (unsigned short*)(w);             // [0,64)
  unsigned short* h2   = (unsigned short*)(w + 97 * MB);   // [97,129) (aprojb dead)
  unsigned short* h3   = (unsigned short*)(w + 65 * MB);   // [65,81) (w2p dead)
  unsigned short* ffob = (unsigned short*)(w);             // [0,16) bf16 (h1 dead)
  unsigned short* ln2b = (unsigned short*)(w + 32 * MB);   // [32,48)

  const float QSCALE = 0.125f * 1.44269504088896f;

  // 1. fused x + QKV-weight casts
  cast_qkvx<<<dim3(5632), dim3(256), 0, stream>>>(x, xb, Wq, Wk, Wv, wbuf);
  // 2. fused QKV GEMM (BM=256)
  gemm8<256, false, 2><<<dim3((MT / 256) * (3072 / 256)), dim3(512), 0, stream>>>(
      xb, wbuf, bq, bk, bv, Qb, Kbf, Vbf, 3072, 1024, QSCALE);
  // 3. fused V^T precompute + softmax denominators
  vtrans_stats<<<dim3(2048 + 1024), dim3(256), 0, stream>>>(Vbf, Vt, Qb, Kbf, lst);
  // 4. attention apply (A summed over batch)
  attn_apply<<<dim3(NH * 16 * 2), dim3(256), 0, stream>>>(Qb, Kbf, Vt, lst, op0, ctx);
  // 5. fused partial-O reduce + Wo cast
  addb_cast<<<dim3(4096 + 512), dim3(256), 0, stream>>>(op0, ctx, Wo, wbuf);
  // 6. output projection (bf16 out)
  gemm8<128, false, 1><<<dim3((MT / 128) * 4), dim3(512), 0, stream>>>(
      ctx, wbuf, bo, nullptr, nullptr, aprojb, nullptr, nullptr, 1024, 1024, 1.0f);
  // 7. fused LN1 (bf16 a + f32 res) + W1/W2/W3/W4/Wl casts
  ln_cast5<<<dim3(16384), dim3(256), 0, stream>>>(
      aprojb, x, gamma, beta, ln1b, W1, W2, W3, W4, Wl, wbuf, w2p);
  // 8-11. FFN chain
  gemm8<256, true, 1><<<dim3((MT / 256) * 16), dim3(512), 0, stream>>>(
      ln1b, wbuf, b1, nullptr, nullptr, h1, nullptr, nullptr, 4096, 1024, 1.0f);
  gemm8<256, true, 1><<<dim3((MT / 256) * 8), dim3(512), 0, stream>>>(
      h1, w2p, b2, nullptr, nullptr, h2, nullptr, nullptr, 2048, 4096, 1.0f);
  gemm8<128, true, 1><<<dim3((MT / 128) * 4), dim3(512), 0, stream>>>(
      h2, wbuf + 4194304, b3, nullptr, nullptr, h3, nullptr, nullptr, 1024, 2048, 1.0f);
  gemm8<128, false, 1><<<dim3((MT / 128) * 4), dim3(512), 0, stream>>>(
      h3, wbuf + 6291456, b4, nullptr, nullptr, ffob, nullptr, nullptr, 1024, 1024, 1.0f);
  // 12. LN2 (bf16 + bf16)
  ln_kernel2<<<dim3(MT), dim3(256), 0, stream>>>(ffob, ln1b, gamma, beta, ln2b);
  // 13. final projection -> d_out fp32
  gemm8<128, false, 0><<<dim3((MT / 128) * 4), dim3(512), 0, stream>>>(
      ln2b, wbuf + 7340032, bl, nullptr, nullptr, out, nullptr, nullptr, 1024, 1024, 1.0f);
}